// Round 1
// baseline (780.739 us; speedup 1.0000x reference)
//
#include <hip/hip_runtime.h>

#define B_ 8
#define C_ 96
#define M_ 4096
#define K_ 9

// ---------------------------------------------------------------------------
// Kernel A: per-point squared norm + fused P/Q projection GEMM.
//   P[m] = x_m @ (W1[0:C] - W1[C:2C]) + b1   (depends only on center point)
//   Q[m] = x_m @ W1[C:2C]                    (depends only on neighbor point)
// x is (B, C, M) channel-major which is exactly the LDS layout we want.
// ---------------------------------------------------------------------------
__global__ __launch_bounds__(256) void prep_kernel(
    const float* __restrict__ x, const float* __restrict__ W1,
    const float* __restrict__ b1,
    float* __restrict__ sq, float* __restrict__ P, float* __restrict__ Q) {
  __shared__ float Xt[C_][64];   // 24 KB, channel-major tile of 64 points
  __shared__ float Wt[C_][64];   // 24 KB, weight tile (combined-cout slice)
  const int b = blockIdx.y, m0 = blockIdx.x * 64;
  const int tid = threadIdx.x;
  const float* xb = x + (size_t)b * C_ * M_;

  for (int i = tid; i < C_ * 16; i += 256) {
    int c = i >> 4, j4 = (i & 15) << 2;
    *(float4*)&Xt[c][j4] = *(const float4*)&xb[(size_t)c * M_ + m0 + j4];
  }
  __syncthreads();

  if (tid < 64) {
    float s = 0.f;
#pragma unroll
    for (int c = 0; c < C_; ++c) { float v = Xt[c][tid]; s += v * v; }
    sq[b * M_ + m0 + tid] = s;
  }

  const int ty = tid >> 4, tx = tid & 15;
  // combined cout axis u in [0,192): u<96 -> P (Wdiff), u>=96 -> Q (W1bot)
  for (int t = 0; t < 3; ++t) {
    const int u0 = t * 64;
    __syncthreads();
    for (int i = tid; i < C_ * 64; i += 256) {
      int cin = i >> 6, j = i & 63;
      int u = u0 + j;
      float w;
      if (u < C_) w = W1[cin * C_ + u] - W1[(C_ + cin) * C_ + u];
      else        w = W1[(C_ + cin) * C_ + (u - C_)];
      Wt[cin][j] = w;
    }
    __syncthreads();
    float acc[4][4] = {};
#pragma unroll 8
    for (int c = 0; c < C_; ++c) {
      float4 rr = *(const float4*)&Xt[c][ty << 2];
      float4 ww = *(const float4*)&Wt[c][tx << 2];
      acc[0][0] += rr.x * ww.x; acc[0][1] += rr.x * ww.y; acc[0][2] += rr.x * ww.z; acc[0][3] += rr.x * ww.w;
      acc[1][0] += rr.y * ww.x; acc[1][1] += rr.y * ww.y; acc[1][2] += rr.y * ww.z; acc[1][3] += rr.y * ww.w;
      acc[2][0] += rr.z * ww.x; acc[2][1] += rr.z * ww.y; acc[2][2] += rr.z * ww.z; acc[2][3] += rr.z * ww.w;
      acc[3][0] += rr.w * ww.x; acc[3][1] += rr.w * ww.y; acc[3][2] += rr.w * ww.z; acc[3][3] += rr.w * ww.w;
    }
#pragma unroll
    for (int i = 0; i < 4; ++i) {
      int m = m0 + (ty << 2) + i;
      size_t base = ((size_t)b * M_ + m) * C_;
#pragma unroll
      for (int j = 0; j < 4; ++j) {
        int u = u0 + (tx << 2) + j;
        float v = acc[i][j];
        if (u < C_) P[base + u] = v + b1[u];
        else        Q[base + (u - C_)] = v;
      }
    }
  }
}

// ---------------------------------------------------------------------------
// Kernel B: KNN. Block = 64 rows of one batch. Loop over 64-col tiles, 4x4
// register micro-tile Gram, rank by sq[n] - 2*dot (sq[m] is row-constant).
// Per-thread top-9 (static-index insertion, stays in VGPRs), 2-pass LDS merge.
// ---------------------------------------------------------------------------
__global__ __launch_bounds__(256) void knn_kernel(
    const float* __restrict__ x, const float* __restrict__ sq,
    int* __restrict__ idxw) {
  __shared__ float smem[2 * C_ * 64 + 128];       // 49.5 KB
  float (*Xr)[64] = (float(*)[64])smem;
  float (*Xc)[64] = (float(*)[64])(smem + C_ * 64);
  float* sqc_s = smem + 2 * C_ * 64;
  const int b = blockIdx.y, r0 = blockIdx.x * 64;
  const int tid = threadIdx.x;
  const int ty = tid >> 4, tx = tid & 15;
  const float* xb = x + (size_t)b * C_ * M_;
  const float* sqb = sq + b * M_;

  for (int i = tid; i < C_ * 16; i += 256) {
    int c = i >> 4, j4 = (i & 15) << 2;
    *(float4*)&Xr[c][j4] = *(const float4*)&xb[(size_t)c * M_ + r0 + j4];
  }

  float tv[4][K_]; int ti[4][K_];
  float tmax[4]; int tpos[4];
#pragma unroll
  for (int i = 0; i < 4; ++i) {
    tmax[i] = 3.4e38f; tpos[i] = 0;
#pragma unroll
    for (int k = 0; k < K_; ++k) { tv[i][k] = 3.4e38f; ti[i][k] = 0; }
  }

  for (int n0 = 0; n0 < M_; n0 += 64) {
    __syncthreads();
    for (int i = tid; i < C_ * 16; i += 256) {
      int c = i >> 4, j4 = (i & 15) << 2;
      *(float4*)&Xc[c][j4] = *(const float4*)&xb[(size_t)c * M_ + n0 + j4];
    }
    if (tid < 64) sqc_s[tid] = sqb[n0 + tid];
    __syncthreads();

    float acc[4][4] = {};
#pragma unroll 8
    for (int c = 0; c < C_; ++c) {
      float4 rr = *(const float4*)&Xr[c][ty << 2];
      float4 cc = *(const float4*)&Xc[c][tx << 2];
      acc[0][0] += rr.x * cc.x; acc[0][1] += rr.x * cc.y; acc[0][2] += rr.x * cc.z; acc[0][3] += rr.x * cc.w;
      acc[1][0] += rr.y * cc.x; acc[1][1] += rr.y * cc.y; acc[1][2] += rr.y * cc.z; acc[1][3] += rr.y * cc.w;
      acc[2][0] += rr.z * cc.x; acc[2][1] += rr.z * cc.y; acc[2][2] += rr.z * cc.z; acc[2][3] += rr.z * cc.w;
      acc[3][0] += rr.w * cc.x; acc[3][1] += rr.w * cc.y; acc[3][2] += rr.w * cc.z; acc[3][3] += rr.w * cc.w;
    }

#pragma unroll
    for (int j = 0; j < 4; ++j) {
      const int n = n0 + (tx << 2) + j;
      const float sn = sqc_s[(tx << 2) + j];
#pragma unroll
      for (int i = 0; i < 4; ++i) {
        float d = sn - 2.f * acc[i][j];
        if (d < tmax[i]) {
          const int p = tpos[i];
#pragma unroll
          for (int k = 0; k < K_; ++k) if (k == p) { tv[i][k] = d; ti[i][k] = n; }
          float mx = tv[i][0]; int mp = 0;
#pragma unroll
          for (int k = 1; k < K_; ++k) if (tv[i][k] > mx) { mx = tv[i][k]; mp = k; }
          tmax[i] = mx; tpos[i] = mp;
        }
      }
    }
  }

  // Final merge: 16 thread-lists of 9 per row -> 9 smallest. Two passes of 32
  // rows reusing smem (stride 145 entries to dodge bank conflicts).
  struct Cand { float v; int id; };
  Cand* buf = (Cand*)smem;
  for (int pass = 0; pass < 2; ++pass) {
    __syncthreads();
    const int tyLo = pass * 8;
    if (ty >= tyLo && ty < tyLo + 8) {
#pragma unroll
      for (int i = 0; i < 4; ++i) {
        int rl = (ty - tyLo) * 4 + i;
#pragma unroll
        for (int k = 0; k < K_; ++k) buf[rl * 145 + tx * K_ + k] = Cand{tv[i][k], ti[i][k]};
      }
    }
    __syncthreads();
    if (tid < 32) {
      float fv[K_]; int fi[K_];
      float mx = 3.4e38f; int mp = 0;
#pragma unroll
      for (int k = 0; k < K_; ++k) { fv[k] = 3.4e38f; fi[k] = 0; }
      for (int s = 0; s < 144; ++s) {
        Cand cd = buf[tid * 145 + s];
        if (cd.v < mx) {
#pragma unroll
          for (int k = 0; k < K_; ++k) if (k == mp) { fv[k] = cd.v; fi[k] = cd.id; }
          float m2 = fv[0]; int p2 = 0;
#pragma unroll
          for (int k = 1; k < K_; ++k) if (fv[k] > m2) { m2 = fv[k]; p2 = k; }
          mx = m2; mp = p2;
        }
      }
      int gr = r0 + pass * 32 + tid;
#pragma unroll
      for (int k = 0; k < K_; ++k) idxw[((size_t)b * M_ + gr) * K_ + k] = fi[k];
    }
  }
}

// ---------------------------------------------------------------------------
// Kernel C: g[m] = mean_k LReLU(P[m] + Q[idx[m,k]]); out = relu(g @ W2 + b2).
// Phase 1: 64 points, threads = (64 pts x 4 channel-groups of 24), g -> LDS.
// Phase 2: 64x96 GEMM vs W2 staged in LDS, coalesced (B,C,M) writes.
// ---------------------------------------------------------------------------
__global__ __launch_bounds__(256) void edge_mlp_kernel(
    const float* __restrict__ P, const float* __restrict__ Q,
    const int* __restrict__ idxw, const float* __restrict__ W2,
    const float* __restrict__ b2, float* __restrict__ out) {
  __shared__ float g_l[C_][64];   // 24 KB, channel-major
  __shared__ float W2t[C_ * C_];  // 36 KB
  const int b = blockIdx.y, m0 = blockIdx.x * 64;
  const int tid = threadIdx.x;

  for (int i = tid; i < (C_ * C_) / 4; i += 256)
    *(float4*)&W2t[i * 4] = *(const float4*)&W2[i * 4];

  const int ml = tid & 63, cg = tid >> 6;  // cg in [0,4): channels cg*24..+23
  const int m = m0 + ml;
  const float* prow = P + ((size_t)b * M_ + m) * C_ + cg * 24;
  float pr[24];
#pragma unroll
  for (int t = 0; t < 24; t += 4) {
    float4 v = *(const float4*)(prow + t);
    pr[t] = v.x; pr[t + 1] = v.y; pr[t + 2] = v.z; pr[t + 3] = v.w;
  }
  float gacc[24] = {};
  const int* irow = idxw + ((size_t)b * M_ + m) * K_;
#pragma unroll
  for (int k = 0; k < K_; ++k) {
    int j = irow[k];
    const float* qrow = Q + ((size_t)b * M_ + j) * C_ + cg * 24;
#pragma unroll
    for (int t = 0; t < 24; t += 4) {
      float4 qv = *(const float4*)(qrow + t);
      float h;
      h = pr[t + 0] + qv.x; gacc[t + 0] += (h >= 0.f) ? h : 0.01f * h;
      h = pr[t + 1] + qv.y; gacc[t + 1] += (h >= 0.f) ? h : 0.01f * h;
      h = pr[t + 2] + qv.z; gacc[t + 2] += (h >= 0.f) ? h : 0.01f * h;
      h = pr[t + 3] + qv.w; gacc[t + 3] += (h >= 0.f) ? h : 0.01f * h;
    }
  }
#pragma unroll
  for (int t = 0; t < 24; ++t) g_l[cg * 24 + t][ml] = gacc[t] * (1.f / 9.f);
  __syncthreads();

  const int ty = tid >> 4, tx = tid & 15;   // rows 4*ty.., cols 6*tx..
  float acc2[4][6] = {};
#pragma unroll 4
  for (int c = 0; c < C_; ++c) {
    float4 rr = *(const float4*)&g_l[c][ty << 2];
    float2 wa = *(const float2*)&W2t[c * C_ + tx * 6];
    float2 wb = *(const float2*)&W2t[c * C_ + tx * 6 + 2];
    float2 wc = *(const float2*)&W2t[c * C_ + tx * 6 + 4];
    float rv[4] = {rr.x, rr.y, rr.z, rr.w};
    float wv[6] = {wa.x, wa.y, wb.x, wb.y, wc.x, wc.y};
#pragma unroll
    for (int i = 0; i < 4; ++i)
#pragma unroll
      for (int j = 0; j < 6; ++j) acc2[i][j] += rv[i] * wv[j];
  }
#pragma unroll
  for (int i = 0; i < 4; ++i) {
    int mm = m0 + (ty << 2) + i;
#pragma unroll
    for (int j = 0; j < 6; ++j) {
      int u = tx * 6 + j;
      float v = acc2[i][j] + b2[u];
      v = fmaxf(v, 0.f);
      out[((size_t)b * C_ + u) * M_ + mm] = v;
    }
  }
}

extern "C" void kernel_launch(void* const* d_in, const int* in_sizes, int n_in,
                              void* d_out, int out_size, void* d_ws, size_t ws_size,
                              hipStream_t stream) {
  const float* x  = (const float*)d_in[0];
  const float* W1 = (const float*)d_in[1];
  const float* b1 = (const float*)d_in[2];
  const float* W2 = (const float*)d_in[3];
  const float* b2 = (const float*)d_in[4];
  float* out = (float*)d_out;

  char* ws = (char*)d_ws;
  float* sq = (float*)ws;                                   // 131072 B
  float* P  = (float*)(ws + 131072);                        // 12582912 B
  float* Q  = (float*)(ws + 131072 + 12582912);             // 12582912 B
  int* idxw = (int*)(ws + 131072 + 2 * 12582912);           // 1179648 B

  dim3 grid(M_ / 64, B_), blk(256);
  prep_kernel<<<grid, blk, 0, stream>>>(x, W1, b1, sq, P, Q);
  knn_kernel<<<grid, blk, 0, stream>>>(x, sq, idxw);
  edge_mlp_kernel<<<grid, blk, 0, stream>>>(P, Q, idxw, W2, b2, out);
}

// Round 2
// 713.468 us; speedup vs baseline: 1.0943x; 1.0943x over previous
//
#include <hip/hip_runtime.h>

#define B_ 8
#define C_ 96
#define M_ 4096
#define K_ 9

// ---------------------------------------------------------------------------
// Kernel A: per-point squared norm + fused P/Q projection GEMM.
//   P[m] = x_m @ (W1[0:C] - W1[C:2C]) + b1   (depends only on center point)
//   Q[m] = x_m @ W1[C:2C]                    (depends only on neighbor point)
// ---------------------------------------------------------------------------
__global__ __launch_bounds__(256) void prep_kernel(
    const float* __restrict__ x, const float* __restrict__ W1,
    const float* __restrict__ b1,
    float* __restrict__ sq, float* __restrict__ P, float* __restrict__ Q) {
  __shared__ float Xt[C_][64];   // 24 KB, channel-major tile of 64 points
  __shared__ float Wt[C_][64];   // 24 KB, weight tile (combined-cout slice)
  const int b = blockIdx.y, m0 = blockIdx.x * 64;
  const int tid = threadIdx.x;
  const float* xb = x + (size_t)b * C_ * M_;

  for (int i = tid; i < C_ * 16; i += 256) {
    int c = i >> 4, j4 = (i & 15) << 2;
    *(float4*)&Xt[c][j4] = *(const float4*)&xb[(size_t)c * M_ + m0 + j4];
  }
  __syncthreads();

  if (tid < 64) {
    float s = 0.f;
#pragma unroll
    for (int c = 0; c < C_; ++c) { float v = Xt[c][tid]; s += v * v; }
    sq[b * M_ + m0 + tid] = s;
  }

  const int ty = tid >> 4, tx = tid & 15;
  // combined cout axis u in [0,192): u<96 -> P (Wdiff), u>=96 -> Q (W1bot)
  for (int t = 0; t < 3; ++t) {
    const int u0 = t * 64;
    __syncthreads();
    for (int i = tid; i < C_ * 64; i += 256) {
      int cin = i >> 6, j = i & 63;
      int u = u0 + j;
      float w;
      if (u < C_) w = W1[cin * C_ + u] - W1[(C_ + cin) * C_ + u];
      else        w = W1[(C_ + cin) * C_ + (u - C_)];
      Wt[cin][j] = w;
    }
    __syncthreads();
    float acc[4][4] = {};
#pragma unroll 8
    for (int c = 0; c < C_; ++c) {
      float4 rr = *(const float4*)&Xt[c][ty << 2];
      float4 ww = *(const float4*)&Wt[c][tx << 2];
      acc[0][0] += rr.x * ww.x; acc[0][1] += rr.x * ww.y; acc[0][2] += rr.x * ww.z; acc[0][3] += rr.x * ww.w;
      acc[1][0] += rr.y * ww.x; acc[1][1] += rr.y * ww.y; acc[1][2] += rr.y * ww.z; acc[1][3] += rr.y * ww.w;
      acc[2][0] += rr.z * ww.x; acc[2][1] += rr.z * ww.y; acc[2][2] += rr.z * ww.z; acc[2][3] += rr.z * ww.w;
      acc[3][0] += rr.w * ww.x; acc[3][1] += rr.w * ww.y; acc[3][2] += rr.w * ww.z; acc[3][3] += rr.w * ww.w;
    }
#pragma unroll
    for (int i = 0; i < 4; ++i) {
      int m = m0 + (ty << 2) + i;
      size_t base = ((size_t)b * M_ + m) * C_;
#pragma unroll
      for (int j = 0; j < 4; ++j) {
        int u = u0 + (tx << 2) + j;
        float v = acc[i][j];
        if (u < C_) P[base + u] = v + b1[u];
        else        Q[base + (u - C_)] = v;
      }
    }
  }
}

// ---------------------------------------------------------------------------
// Kernel B: KNN. Block = 64 rows of one batch. Thread = (row, colgroup of 16):
// each thread owns exactly ONE top-9 list (stays in VGPRs, no spill).
//   rr read: 64 consecutive dwords per wave (2-way bank alias = free)
//   cc read: wave-uniform float4s (cg constant per wave) -> broadcast
// Rank by sq[n] - 2*dot (sq[m] is row-constant). Merge 4 lists/row via LDS.
// ---------------------------------------------------------------------------
__global__ __launch_bounds__(256) void knn_kernel(
    const float* __restrict__ x, const float* __restrict__ sq,
    int* __restrict__ idxw) {
  __shared__ float smem[2 * C_ * 64 + 64];        // 49.4 KB -> 3 blocks/CU
  float (*Xr)[64] = (float(*)[64])smem;
  float (*Xc)[64] = (float(*)[64])(smem + C_ * 64);
  float* sqc_s = smem + 2 * C_ * 64;
  const int b = blockIdx.y, r0 = blockIdx.x * 64;
  const int tid = threadIdx.x;
  const int row = tid & 63, cg = tid >> 6;        // cg is wave-uniform
  const float* xb = x + (size_t)b * C_ * M_;
  const float* sqb = sq + b * M_;

  for (int i = tid; i < C_ * 16; i += 256) {
    int c = i >> 4, j4 = (i & 15) << 2;
    *(float4*)&Xr[c][j4] = *(const float4*)&xb[(size_t)c * M_ + r0 + j4];
  }

  float tv[K_]; int ti[K_];
  float tmax = 3.4e38f; int tpos = 0;
#pragma unroll
  for (int k = 0; k < K_; ++k) { tv[k] = 3.4e38f; ti[k] = 0; }

  for (int n0 = 0; n0 < M_; n0 += 64) {
    __syncthreads();
    for (int i = tid; i < C_ * 16; i += 256) {
      int c = i >> 4, j4 = (i & 15) << 2;
      *(float4*)&Xc[c][j4] = *(const float4*)&xb[(size_t)c * M_ + n0 + j4];
    }
    if (tid < 64) sqc_s[tid] = sqb[n0 + tid];
    __syncthreads();

    float acc[16] = {};
#pragma unroll 4
    for (int c = 0; c < C_; ++c) {
      float rr = Xr[c][row];
      float4 c0 = *(const float4*)&Xc[c][cg * 16 + 0];
      float4 c1 = *(const float4*)&Xc[c][cg * 16 + 4];
      float4 c2 = *(const float4*)&Xc[c][cg * 16 + 8];
      float4 c3 = *(const float4*)&Xc[c][cg * 16 + 12];
      acc[0]  += rr * c0.x;  acc[1]  += rr * c0.y;  acc[2]  += rr * c0.z;  acc[3]  += rr * c0.w;
      acc[4]  += rr * c1.x;  acc[5]  += rr * c1.y;  acc[6]  += rr * c1.z;  acc[7]  += rr * c1.w;
      acc[8]  += rr * c2.x;  acc[9]  += rr * c2.y;  acc[10] += rr * c2.z;  acc[11] += rr * c2.w;
      acc[12] += rr * c3.x;  acc[13] += rr * c3.y;  acc[14] += rr * c3.z;  acc[15] += rr * c3.w;
    }

#pragma unroll
    for (int j = 0; j < 16; ++j) {
      const int n = n0 + cg * 16 + j;
      const float d = sqc_s[cg * 16 + j] - 2.f * acc[j];
      if (d < tmax) {
        const int p = tpos;
#pragma unroll
        for (int k = 0; k < K_; ++k) if (k == p) { tv[k] = d; ti[k] = n; }
        float mx = tv[0]; int mp = 0;
#pragma unroll
        for (int k = 1; k < K_; ++k) if (tv[k] > mx) { mx = tv[k]; mp = k; }
        tmax = mx; tpos = mp;
      }
    }
  }

  // Merge the 4 colgroup lists per row (stride 37 -> 2-way banking = free).
  __syncthreads();
  float* mv = smem;                       // [64][37] values
  int*   mi = (int*)(smem + 64 * 37);     // [64][37] indices
#pragma unroll
  for (int k = 0; k < K_; ++k) {
    mv[row * 37 + cg * K_ + k] = tv[k];
    mi[row * 37 + cg * K_ + k] = ti[k];
  }
  __syncthreads();
  if (tid < 64) {
    float fv[K_]; int fi[K_];
    float mx = 3.4e38f; int mp = 0;
#pragma unroll
    for (int k = 0; k < K_; ++k) { fv[k] = 3.4e38f; fi[k] = 0; }
    for (int s = 0; s < 36; ++s) {
      float v = mv[tid * 37 + s]; int id = mi[tid * 37 + s];
      if (v < mx) {
#pragma unroll
        for (int k = 0; k < K_; ++k) if (k == mp) { fv[k] = v; fi[k] = id; }
        float m2 = fv[0]; int p2 = 0;
#pragma unroll
        for (int k = 1; k < K_; ++k) if (fv[k] > m2) { m2 = fv[k]; p2 = k; }
        mx = m2; mp = p2;
      }
    }
#pragma unroll
    for (int k = 0; k < K_; ++k)
      idxw[((size_t)b * M_ + r0 + tid) * K_ + k] = fi[k];
  }
}

// ---------------------------------------------------------------------------
// Kernel C: g[m] = mean_k LReLU(P[m] + Q[idx[m,k]]); out = relu(g @ W2 + b2).
// ---------------------------------------------------------------------------
__global__ __launch_bounds__(256) void edge_mlp_kernel(
    const float* __restrict__ P, const float* __restrict__ Q,
    const int* __restrict__ idxw, const float* __restrict__ W2,
    const float* __restrict__ b2, float* __restrict__ out) {
  __shared__ float g_l[C_][64];   // 24 KB, channel-major
  __shared__ float W2t[C_ * C_];  // 36 KB
  const int b = blockIdx.y, m0 = blockIdx.x * 64;
  const int tid = threadIdx.x;

  for (int i = tid; i < (C_ * C_) / 4; i += 256)
    *(float4*)&W2t[i * 4] = *(const float4*)&W2[i * 4];

  const int ml = tid & 63, cg = tid >> 6;  // cg in [0,4): channels cg*24..+23
  const int m = m0 + ml;
  const float* prow = P + ((size_t)b * M_ + m) * C_ + cg * 24;
  float pr[24];
#pragma unroll
  for (int t = 0; t < 24; t += 4) {
    float4 v = *(const float4*)(prow + t);
    pr[t] = v.x; pr[t + 1] = v.y; pr[t + 2] = v.z; pr[t + 3] = v.w;
  }
  float gacc[24] = {};
  const int* irow = idxw + ((size_t)b * M_ + m) * K_;
#pragma unroll
  for (int k = 0; k < K_; ++k) {
    int j = irow[k];
    const float* qrow = Q + ((size_t)b * M_ + j) * C_ + cg * 24;
#pragma unroll
    for (int t = 0; t < 24; t += 4) {
      float4 qv = *(const float4*)(qrow + t);
      float h;
      h = pr[t + 0] + qv.x; gacc[t + 0] += (h >= 0.f) ? h : 0.01f * h;
      h = pr[t + 1] + qv.y; gacc[t + 1] += (h >= 0.f) ? h : 0.01f * h;
      h = pr[t + 2] + qv.z; gacc[t + 2] += (h >= 0.f) ? h : 0.01f * h;
      h = pr[t + 3] + qv.w; gacc[t + 3] += (h >= 0.f) ? h : 0.01f * h;
    }
  }
#pragma unroll
  for (int t = 0; t < 24; ++t) g_l[cg * 24 + t][ml] = gacc[t] * (1.f / 9.f);
  __syncthreads();

  const int ty = tid >> 4, tx = tid & 15;   // rows 4*ty.., cols 6*tx..
  float acc2[4][6] = {};
#pragma unroll 4
  for (int c = 0; c < C_; ++c) {
    float4 rr = *(const float4*)&g_l[c][ty << 2];
    float2 wa = *(const float2*)&W2t[c * C_ + tx * 6];
    float2 wb = *(const float2*)&W2t[c * C_ + tx * 6 + 2];
    float2 wc = *(const float2*)&W2t[c * C_ + tx * 6 + 4];
    float rv[4] = {rr.x, rr.y, rr.z, rr.w};
    float wv[6] = {wa.x, wa.y, wb.x, wb.y, wc.x, wc.y};
#pragma unroll
    for (int i = 0; i < 4; ++i)
#pragma unroll
      for (int j = 0; j < 6; ++j) acc2[i][j] += rv[i] * wv[j];
  }
#pragma unroll
  for (int i = 0; i < 4; ++i) {
    int mm = m0 + (ty << 2) + i;
#pragma unroll
    for (int j = 0; j < 6; ++j) {
      int u = tx * 6 + j;
      float v = acc2[i][j] + b2[u];
      v = fmaxf(v, 0.f);
      out[((size_t)b * C_ + u) * M_ + mm] = v;
    }
  }
}

extern "C" void kernel_launch(void* const* d_in, const int* in_sizes, int n_in,
                              void* d_out, int out_size, void* d_ws, size_t ws_size,
                              hipStream_t stream) {
  const float* x  = (const float*)d_in[0];
  const float* W1 = (const float*)d_in[1];
  const float* b1 = (const float*)d_in[2];
  const float* W2 = (const float*)d_in[3];
  const float* b2 = (const float*)d_in[4];
  float* out = (float*)d_out;

  char* ws = (char*)d_ws;
  float* sq = (float*)ws;                                   // 131072 B
  float* P  = (float*)(ws + 131072);                        // 12582912 B
  float* Q  = (float*)(ws + 131072 + 12582912);             // 12582912 B
  int* idxw = (int*)(ws + 131072 + 2 * 12582912);           // 1179648 B

  dim3 grid(M_ / 64, B_), blk(256);
  prep_kernel<<<grid, blk, 0, stream>>>(x, W1, b1, sq, P, Q);
  knn_kernel<<<grid, blk, 0, stream>>>(x, sq, idxw);
  edge_mlp_kernel<<<grid, blk, 0, stream>>>(P, Q, idxw, W2, b2, out);
}

// Round 6
// 301.142 us; speedup vs baseline: 2.5926x; 2.3692x over previous
//
#include <hip/hip_runtime.h>

#define B_ 8
#define C_ 96
#define CP_ 104   // padded channels: 208 B/point; pad never read by MFMA (k<96); 208B stride -> 2-way LDS banking
#define M_ 4096
#define K_ 9

typedef _Float16 f16x8 __attribute__((ext_vector_type(8)));
typedef float f32x4 __attribute__((ext_vector_type(4)));

typedef const __attribute__((address_space(1))) unsigned int* as1_u32p;
typedef __attribute__((address_space(3))) unsigned int* as3_u32p;

__device__ inline void g2lds16(const void* g, void* l) {
  __builtin_amdgcn_global_load_lds((as1_u32p)g, (as3_u32p)l, 16, 0, 0);
}

// ---------------------------------------------------------------------------
// prep1: per-point squared norm + fp16 split (hi = f16(x), lo = f16(x - hi))
// written point-major [B][M][CP_] so MFMA fragments & staging are linear.
// ---------------------------------------------------------------------------
__global__ __launch_bounds__(256) void prep1_kernel(
    const float* __restrict__ x, float* __restrict__ sq,
    unsigned short* __restrict__ xhi, unsigned short* __restrict__ xlo) {
  __shared__ float Xt[C_][64];
  const int b = blockIdx.y, m0 = blockIdx.x * 64, tid = threadIdx.x;
  const float* xb = x + (size_t)b * C_ * M_;
  for (int i = tid; i < C_ * 16; i += 256) {
    int c = i >> 4, j4 = (i & 15) << 2;
    *(float4*)&Xt[c][j4] = *(const float4*)&xb[(size_t)c * M_ + m0 + j4];
  }
  __syncthreads();
  if (tid < 64) {
    float s = 0.f;
#pragma unroll
    for (int c = 0; c < C_; ++c) { float v = Xt[c][tid]; s += v * v; }
    sq[b * M_ + m0 + tid] = s;
  }
  const int p = tid & 63, part = tid >> 6;  // thread owns point p, 24 channels
  union { unsigned short u[24]; uint4 q[3]; } hb, lb;
#pragma unroll
  for (int i = 0; i < 24; ++i) {
    float v = Xt[part * 24 + i][p];
    _Float16 h = (_Float16)v;
    _Float16 l = (_Float16)(v - (float)h);
    hb.u[i] = __builtin_bit_cast(unsigned short, h);
    lb.u[i] = __builtin_bit_cast(unsigned short, l);
  }
  size_t base = ((size_t)b * M_ + m0 + p) * CP_ + part * 24;
#pragma unroll
  for (int i = 0; i < 3; ++i) {
    *(uint4*)&xhi[base + i * 8] = hb.q[i];
    *(uint4*)&xlo[base + i * 8] = lb.q[i];
  }
}

// ---------------------------------------------------------------------------
// knn: Gram via 3-pass fp16-split MFMA (hh + hl + lh), d = sq[n] - 2*dot into
// LDS D-tile, per-thread top-9 selection. DOUBLE-BUFFERED staging: prefetch
// of tile t+1 writes S[(t+1)&1] while tile t reads S[t&1] -> no WAR hazard
// regardless of compiler scheduling around barriers.
// ---------------------------------------------------------------------------
__global__ __launch_bounds__(256, 2) void knn_kernel(
    const unsigned short* __restrict__ xhi, const unsigned short* __restrict__ xlo,
    const float* __restrict__ sq, int* __restrict__ idxw) {
  __shared__ struct { unsigned short bhi[64 * CP_]; unsigned short blo[64 * CP_]; } S[2]; // 53248 B
  __shared__ float Dt[64 * 65];    // stride 65: selection reads conflict-free
  __shared__ float sqc[2][64];
  const int b = blockIdx.y, r0 = blockIdx.x * 64, tid = threadIdx.x;
  const int lane = tid & 63, w = tid >> 6;
  const int fp = lane & 15, kg = lane >> 4;
  const size_t bm = (size_t)b * M_;

  // ---- A fragments: 64 rows x 96 ch, hi+lo, resident in VGPRs (96 VGPRs) ----
  f16x8 ahi[4][3], alo[4][3];
#pragma unroll
  for (int rs = 0; rs < 4; ++rs)
#pragma unroll
    for (int kt = 0; kt < 3; ++kt) {
      size_t off = (bm + r0 + rs * 16 + fp) * CP_ + kt * 32 + kg * 8;
      ahi[rs][kt] = *(const f16x8*)&xhi[off];
      alo[rs][kt] = *(const f16x8*)&xlo[off];
    }

  float tv[K_]; int ti[K_]; float tmax = 3.4e38f; int tpos = 0;
#pragma unroll
  for (int k = 0; k < K_; ++k) { tv[k] = 3.4e38f; ti[k] = 0; }

  auto stage = [&](int n0, int pp) {
    const unsigned short* sh = xhi + (bm + n0) * CP_;
    const unsigned short* sl = xlo + (bm + n0) * CP_;
    unsigned short* dh = S[pp].bhi;
    unsigned short* dl = S[pp].blo;
#pragma unroll
    for (int it = 0; it < 3; ++it) {
      int ch = tid + it * 256;                 // 16B chunk index (832 total)
      g2lds16(sh + ch * 8, dh + ch * 8);
      g2lds16(sl + ch * 8, dl + ch * 8);
    }
    if (tid < 64) {
      int ch = 768 + tid;
      g2lds16(sh + ch * 8, dh + ch * 8);
      g2lds16(sl + ch * 8, dl + ch * 8);
      sqc[pp][tid] = sq[bm + n0 + tid];
    }
  };

  stage(0, 0);
  for (int t = 0; t < 64; ++t) {
    const int n0 = t * 64;
    const int cur = t & 1;
    __syncthreads();   // stage(t) drained (vmcnt(0) before barrier); Dt free (selection t-1 done)

    // ---- B fragments for this tile, then issue prefetch into other buffer ----
    f16x8 bhi[3], blo[3];
#pragma unroll
    for (int kt = 0; kt < 3; ++kt) {
      int boff = (w * 16 + fp) * CP_ + kt * 32 + kg * 8;
      bhi[kt] = *(const f16x8*)&S[cur].bhi[boff];
      blo[kt] = *(const f16x8*)&S[cur].blo[boff];
    }
    if (t < 63) stage(n0 + 64, cur ^ 1);   // DMA overlaps MFMA phase below

    const int colg = w * 16 + fp;
    const float scol = sqc[cur][colg];
#pragma unroll
    for (int rs = 0; rs < 4; ++rs) {
      f32x4 acc = {0.f, 0.f, 0.f, 0.f};
#pragma unroll
      for (int kt = 0; kt < 3; ++kt) {
        acc = __builtin_amdgcn_mfma_f32_16x16x32_f16(ahi[rs][kt], bhi[kt], acc, 0, 0, 0);
        acc = __builtin_amdgcn_mfma_f32_16x16x32_f16(ahi[rs][kt], blo[kt], acc, 0, 0, 0);
        acc = __builtin_amdgcn_mfma_f32_16x16x32_f16(alo[rs][kt], bhi[kt], acc, 0, 0, 0);
      }
#pragma unroll
      for (int r = 0; r < 4; ++r) {           // C/D: col=lane&15, row=(lane>>4)*4+r
        int row = rs * 16 + kg * 4 + r;
        Dt[row * 65 + colg] = scol - 2.f * acc[r];
      }
    }
    __syncthreads();   // Dt ready

    // ---- selection: thread = (row=lane, quarter=w), one top-9 list ----
    const float* drow = &Dt[lane * 65 + w * 16];
#pragma unroll
    for (int j = 0; j < 16; ++j) {
      float d = drow[j];
      if (d < tmax) {
        int n = n0 + w * 16 + j;
        const int pz = tpos;
#pragma unroll
        for (int k = 0; k < K_; ++k) if (k == pz) { tv[k] = d; ti[k] = n; }
        float mx = tv[0]; int mp = 0;
#pragma unroll
        for (int k = 1; k < K_; ++k) if (tv[k] > mx) { mx = tv[k]; mp = k; }
        tmax = mx; tpos = mp;
      }
    }
  }

  // ---- merge 4 quarter-lists per row (stride 37 -> 2-way banking = free) ----
  __syncthreads();
  float* mv = (float*)&S[0];                    // reuse dead staging LDS
  int*   mi = (int*)((char*)&S[0] + 64 * 37 * 4);
#pragma unroll
  for (int k = 0; k < K_; ++k) {
    mv[lane * 37 + w * K_ + k] = tv[k];
    mi[lane * 37 + w * K_ + k] = ti[k];
  }
  __syncthreads();
  if (tid < 64) {
    float fv[K_]; int fi[K_];
    float mx = 3.4e38f; int mp = 0;
#pragma unroll
    for (int k = 0; k < K_; ++k) { fv[k] = 3.4e38f; fi[k] = 0; }
    for (int s = 0; s < 36; ++s) {
      float v = mv[tid * 37 + s]; int id = mi[tid * 37 + s];
      if (v < mx) {
#pragma unroll
        for (int k = 0; k < K_; ++k) if (k == mp) { fv[k] = v; fi[k] = id; }
        float m2 = fv[0]; int p2 = 0;
#pragma unroll
        for (int k = 1; k < K_; ++k) if (fv[k] > m2) { m2 = fv[k]; p2 = k; }
        mx = m2; mp = p2;
      }
    }
#pragma unroll
    for (int k = 0; k < K_; ++k)
      idxw[((size_t)b * M_ + r0 + tid) * K_ + k] = fi[k];
  }
}

// ---------------------------------------------------------------------------
// prep2: P/Q projection GEMM (runs AFTER knn; reuses the dead xhi/xlo region).
//   P[m] = x_m @ (W1[0:C] - W1[C:2C]) + b1,  Q[m] = x_m @ W1[C:2C]
// ---------------------------------------------------------------------------
__global__ __launch_bounds__(256) void prep2_kernel(
    const float* __restrict__ x, const float* __restrict__ W1,
    const float* __restrict__ b1, float* __restrict__ P, float* __restrict__ Q) {
  __shared__ float Xt[C_][64];
  __shared__ float Wt[C_][64];
  const int b = blockIdx.y, m0 = blockIdx.x * 64;
  const int tid = threadIdx.x;
  const float* xb = x + (size_t)b * C_ * M_;

  for (int i = tid; i < C_ * 16; i += 256) {
    int c = i >> 4, j4 = (i & 15) << 2;
    *(float4*)&Xt[c][j4] = *(const float4*)&xb[(size_t)c * M_ + m0 + j4];
  }

  const int ty = tid >> 4, tx = tid & 15;
  for (int t = 0; t < 3; ++t) {
    const int u0 = t * 64;
    __syncthreads();
    for (int i = tid; i < C_ * 64; i += 256) {
      int cin = i >> 6, j = i & 63;
      int u = u0 + j;
      float wv;
      if (u < C_) wv = W1[cin * C_ + u] - W1[(C_ + cin) * C_ + u];
      else        wv = W1[(C_ + cin) * C_ + (u - C_)];
      Wt[cin][j] = wv;
    }
    __syncthreads();
    float acc[4][4] = {};
#pragma unroll 8
    for (int c = 0; c < C_; ++c) {
      float4 rr = *(const float4*)&Xt[c][ty << 2];
      float4 ww = *(const float4*)&Wt[c][tx << 2];
      acc[0][0] += rr.x * ww.x; acc[0][1] += rr.x * ww.y; acc[0][2] += rr.x * ww.z; acc[0][3] += rr.x * ww.w;
      acc[1][0] += rr.y * ww.x; acc[1][1] += rr.y * ww.y; acc[1][2] += rr.y * ww.z; acc[1][3] += rr.y * ww.w;
      acc[2][0] += rr.z * ww.x; acc[2][1] += rr.z * ww.y; acc[2][2] += rr.z * ww.z; acc[2][3] += rr.z * ww.w;
      acc[3][0] += rr.w * ww.x; acc[3][1] += rr.w * ww.y; acc[3][2] += rr.w * ww.z; acc[3][3] += rr.w * ww.w;
    }
#pragma unroll
    for (int i = 0; i < 4; ++i) {
      int m = m0 + (ty << 2) + i;
      size_t base = ((size_t)b * M_ + m) * C_;
#pragma unroll
      for (int j = 0; j < 4; ++j) {
        int u = u0 + (tx << 2) + j;
        float v = acc[i][j];
        if (u < C_) P[base + u] = v + b1[u];
        else        Q[base + (u - C_)] = v;
      }
    }
  }
}

// ---------------------------------------------------------------------------
// edge_mlp: g[m] = mean_k LReLU(P[m] + Q[idx[m,k]]); out = relu(g @ W2 + b2).
// ---------------------------------------------------------------------------
__global__ __launch_bounds__(256) void edge_mlp_kernel(
    const float* __restrict__ P, const float* __restrict__ Q,
    const int* __restrict__ idxw, const float* __restrict__ W2,
    const float* __restrict__ b2, float* __restrict__ out) {
  __shared__ float g_l[C_][64];
  __shared__ float W2t[C_ * C_];
  const int b = blockIdx.y, m0 = blockIdx.x * 64;
  const int tid = threadIdx.x;

  for (int i = tid; i < (C_ * C_) / 4; i += 256)
    *(float4*)&W2t[i * 4] = *(const float4*)&W2[i * 4];

  const int ml = tid & 63, cg = tid >> 6;
  const int m = m0 + ml;
  const float* prow = P + ((size_t)b * M_ + m) * C_ + cg * 24;
  float pr[24];
#pragma unroll
  for (int t = 0; t < 24; t += 4) {
    float4 v = *(const float4*)(prow + t);
    pr[t] = v.x; pr[t + 1] = v.y; pr[t + 2] = v.z; pr[t + 3] = v.w;
  }
  float gacc[24] = {};
  const int* irow = idxw + ((size_t)b * M_ + m) * K_;
#pragma unroll
  for (int k = 0; k < K_; ++k) {
    int j = irow[k];
    const float* qrow = Q + ((size_t)b * M_ + j) * C_ + cg * 24;
#pragma unroll
    for (int t = 0; t < 24; t += 4) {
      float4 qv = *(const float4*)(qrow + t);
      float h;
      h = pr[t + 0] + qv.x; gacc[t + 0] += (h >= 0.f) ? h : 0.01f * h;
      h = pr[t + 1] + qv.y; gacc[t + 1] += (h >= 0.f) ? h : 0.01f * h;
      h = pr[t + 2] + qv.z; gacc[t + 2] += (h >= 0.f) ? h : 0.01f * h;
      h = pr[t + 3] + qv.w; gacc[t + 3] += (h >= 0.f) ? h : 0.01f * h;
    }
  }
#pragma unroll
  for (int t = 0; t < 24; ++t) g_l[cg * 24 + t][ml] = gacc[t] * (1.f / 9.f);
  __syncthreads();

  const int ty = tid >> 4, tx = tid & 15;
  float acc2[4][6] = {};
#pragma unroll 4
  for (int c = 0; c < C_; ++c) {
    float4 rr = *(const float4*)&g_l[c][ty << 2];
    float2 wa = *(const float2*)&W2t[c * C_ + tx * 6];
    float2 wb = *(const float2*)&W2t[c * C_ + tx * 6 + 2];
    float2 wc = *(const float2*)&W2t[c * C_ + tx * 6 + 4];
    float rv[4] = {rr.x, rr.y, rr.z, rr.w};
    float wv[6] = {wa.x, wa.y, wb.x, wb.y, wc.x, wc.y};
#pragma unroll
    for (int i = 0; i < 4; ++i)
#pragma unroll
      for (int j = 0; j < 6; ++j) acc2[i][j] += rv[i] * wv[j];
  }
#pragma unroll
  for (int i = 0; i < 4; ++i) {
    int mm = m0 + (ty << 2) + i;
#pragma unroll
    for (int j = 0; j < 6; ++j) {
      int u = tx * 6 + j;
      float v = acc2[i][j] + b2[u];
      v = fmaxf(v, 0.f);
      out[((size_t)b * C_ + u) * M_ + mm] = v;
    }
  }
}

extern "C" void kernel_launch(void* const* d_in, const int* in_sizes, int n_in,
                              void* d_out, int out_size, void* d_ws, size_t ws_size,
                              hipStream_t stream) {
  const float* x  = (const float*)d_in[0];
  const float* W1 = (const float*)d_in[1];
  const float* b1 = (const float*)d_in[2];
  const float* W2 = (const float*)d_in[3];
  const float* b2 = (const float*)d_in[4];
  float* out = (float*)d_out;

  // ws layout — peak 26,476,544 B (== round-1/2 proven footprint; do NOT grow):
  //   [0,        131072)    sq
  //   [131072,   1310720)   idxw
  //   phase 1 (prep1+knn):  xhi [1310720, 8126464), xlo [8126464, 14942208)
  //   phase 2 (prep2+mlp):  P   [1310720, 13893632), Q  [13893632, 26476544)
  //   (P/Q alias the dead xhi/xlo region; kernels are stream-ordered)
  char* ws = (char*)d_ws;
  float* sq  = (float*)ws;
  int* idxw  = (int*)(ws + 131072);
  unsigned short* xhi = (unsigned short*)(ws + 1310720);
  unsigned short* xlo = (unsigned short*)(ws + 8126464);
  float* P = (float*)(ws + 1310720);
  float* Q = (float*)(ws + 13893632);

  dim3 grid(M_ / 64, B_), blk(256);
  prep1_kernel<<<grid, blk, 0, stream>>>(x, sq, xhi, xlo);
  knn_kernel<<<grid, blk, 0, stream>>>(xhi, xlo, sq, idxw);
  prep2_kernel<<<grid, blk, 0, stream>>>(x, W1, b1, P, Q);
  edge_mlp_kernel<<<grid, blk, 0, stream>>>(P, Q, idxw, W2, b2, out);
}

// Round 7
// 294.421 us; speedup vs baseline: 2.6518x; 1.0228x over previous
//
#include <hip/hip_runtime.h>

#define B_ 8
#define C_ 96
#define CP_ 104   // padded channels: 208 B/point; pad never read by MFMA (k<96)
#define M_ 4096
#define K_ 9

typedef _Float16 f16x8 __attribute__((ext_vector_type(8)));
typedef float f32x4 __attribute__((ext_vector_type(4)));

typedef const __attribute__((address_space(1))) unsigned int* as1_u32p;
typedef __attribute__((address_space(3))) unsigned int* as3_u32p;

__device__ inline void g2lds16(const void* g, void* l) {
  __builtin_amdgcn_global_load_lds((as1_u32p)g, (as3_u32p)l, 16, 0, 0);
}

// full list-insert (assumes dv < tmax already checked)
#define INSERT(dv, nv) do {                                                   \
    const int pz_ = tpos;                                                     \
    _Pragma("unroll")                                                         \
    for (int k_ = 0; k_ < K_; ++k_) if (k_ == pz_) { tv[k_] = (dv); ti[k_] = (nv); } \
    float mx_ = tv[0]; int mp_ = 0;                                           \
    _Pragma("unroll")                                                         \
    for (int k_ = 1; k_ < K_; ++k_) if (tv[k_] > mx_) { mx_ = tv[k_]; mp_ = k_; } \
    tmax = mx_; tpos = mp_;                                                   \
  } while (0)

// ---------------------------------------------------------------------------
// prep1: per-point squared norm + fp16 split (hi = f16(x), lo = f16(x - hi))
// written point-major [B][M][CP_] so MFMA fragments & staging are linear.
// ---------------------------------------------------------------------------
__global__ __launch_bounds__(256) void prep1_kernel(
    const float* __restrict__ x, float* __restrict__ sq,
    unsigned short* __restrict__ xhi, unsigned short* __restrict__ xlo) {
  __shared__ float Xt[C_][64];
  const int b = blockIdx.y, m0 = blockIdx.x * 64, tid = threadIdx.x;
  const float* xb = x + (size_t)b * C_ * M_;
  for (int i = tid; i < C_ * 16; i += 256) {
    int c = i >> 4, j4 = (i & 15) << 2;
    *(float4*)&Xt[c][j4] = *(const float4*)&xb[(size_t)c * M_ + m0 + j4];
  }
  __syncthreads();
  if (tid < 64) {
    float s = 0.f;
#pragma unroll
    for (int c = 0; c < C_; ++c) { float v = Xt[c][tid]; s += v * v; }
    sq[b * M_ + m0 + tid] = s;
  }
  const int p = tid & 63, part = tid >> 6;  // thread owns point p, 24 channels
  union { unsigned short u[24]; uint4 q[3]; } hb, lb;
#pragma unroll
  for (int i = 0; i < 24; ++i) {
    float v = Xt[part * 24 + i][p];
    _Float16 h = (_Float16)v;
    _Float16 l = (_Float16)(v - (float)h);
    hb.u[i] = __builtin_bit_cast(unsigned short, h);
    lb.u[i] = __builtin_bit_cast(unsigned short, l);
  }
  size_t base = ((size_t)b * M_ + m0 + p) * CP_ + part * 24;
#pragma unroll
  for (int i = 0; i < 3; ++i) {
    *(uint4*)&xhi[base + i * 8] = hb.q[i];
    *(uint4*)&xlo[base + i * 8] = lb.q[i];
  }
}

// ---------------------------------------------------------------------------
// knn: Gram via 3-pass fp16-split MFMA (hh + hl + lh), d = sq[n] - 2*dot into
// LDS D-tile, per-thread top-9 selection with cap-2 deferred-insert buffer
// (cuts wave-divergent insert-body executions ~4x). Double-buffered staging.
// ---------------------------------------------------------------------------
__global__ __launch_bounds__(256, 2) void knn_kernel(
    const unsigned short* __restrict__ xhi, const unsigned short* __restrict__ xlo,
    const float* __restrict__ sq, int* __restrict__ idxw) {
  __shared__ struct { unsigned short bhi[64 * CP_]; unsigned short blo[64 * CP_]; } S[2]; // 53248 B
  __shared__ float Dt[64 * 65];    // stride 65: selection reads conflict-free
  __shared__ float sqc[2][64];
  const int b = blockIdx.y, r0 = blockIdx.x * 64, tid = threadIdx.x;
  const int lane = tid & 63, w = tid >> 6;
  const int fp = lane & 15, kg = lane >> 4;
  const size_t bm = (size_t)b * M_;

  // ---- A fragments: 64 rows x 96 ch, hi+lo, resident in VGPRs (96 VGPRs) ----
  f16x8 ahi[4][3], alo[4][3];
#pragma unroll
  for (int rs = 0; rs < 4; ++rs)
#pragma unroll
    for (int kt = 0; kt < 3; ++kt) {
      size_t off = (bm + r0 + rs * 16 + fp) * CP_ + kt * 32 + kg * 8;
      ahi[rs][kt] = *(const f16x8*)&xhi[off];
      alo[rs][kt] = *(const f16x8*)&xlo[off];
    }

  float tv[K_]; int ti[K_]; float tmax = 3.4e38f; int tpos = 0;
#pragma unroll
  for (int k = 0; k < K_; ++k) { tv[k] = 3.4e38f; ti[k] = 0; }

  auto stage = [&](int n0, int pp) {
    const unsigned short* sh = xhi + (bm + n0) * CP_;
    const unsigned short* sl = xlo + (bm + n0) * CP_;
    unsigned short* dh = S[pp].bhi;
    unsigned short* dl = S[pp].blo;
#pragma unroll
    for (int it = 0; it < 3; ++it) {
      int ch = tid + it * 256;                 // 16B chunk index (832 total)
      g2lds16(sh + ch * 8, dh + ch * 8);
      g2lds16(sl + ch * 8, dl + ch * 8);
    }
    if (tid < 64) {
      int ch = 768 + tid;
      g2lds16(sh + ch * 8, dh + ch * 8);
      g2lds16(sl + ch * 8, dl + ch * 8);
      sqc[pp][tid] = sq[bm + n0 + tid];
    }
  };

  stage(0, 0);
  for (int t = 0; t < 64; ++t) {
    const int n0 = t * 64;
    const int cur = t & 1;
    __syncthreads();   // stage(t) drained (vmcnt(0) before barrier); Dt free

    // ---- B fragments for this tile, then issue prefetch into other buffer ----
    f16x8 bhi[3], blo[3];
#pragma unroll
    for (int kt = 0; kt < 3; ++kt) {
      int boff = (w * 16 + fp) * CP_ + kt * 32 + kg * 8;
      bhi[kt] = *(const f16x8*)&S[cur].bhi[boff];
      blo[kt] = *(const f16x8*)&S[cur].blo[boff];
    }
    if (t < 63) stage(n0 + 64, cur ^ 1);   // DMA overlaps MFMA phase below

    const int colg = w * 16 + fp;
    const float scol = sqc[cur][colg];
#pragma unroll
    for (int rs = 0; rs < 4; ++rs) {
      f32x4 acc = {0.f, 0.f, 0.f, 0.f};
#pragma unroll
      for (int kt = 0; kt < 3; ++kt) {
        acc = __builtin_amdgcn_mfma_f32_16x16x32_f16(ahi[rs][kt], bhi[kt], acc, 0, 0, 0);
        acc = __builtin_amdgcn_mfma_f32_16x16x32_f16(ahi[rs][kt], blo[kt], acc, 0, 0, 0);
        acc = __builtin_amdgcn_mfma_f32_16x16x32_f16(alo[rs][kt], bhi[kt], acc, 0, 0, 0);
      }
#pragma unroll
      for (int r = 0; r < 4; ++r) {           // C/D: col=lane&15, row=(lane>>4)*4+r
        int row = rs * 16 + kg * 4 + r;
        Dt[row * 65 + colg] = scol - 2.f * acc[r];
      }
    }
    __syncthreads();   // Dt ready

    // ---- selection: thread = (row=lane, quarter=w), cap-2 deferred insert ----
    const float* drow = &Dt[lane * 65 + w * 16];
    float b0d = 0.f, b1d = 0.f; int b0n = 0, b1n = 0, bcnt = 0;
#pragma unroll
    for (int j = 0; j < 16; ++j) {
      float d = drow[j];
      if (d < tmax) {                         // push (cheap); wave-any frequent
        const int n = n0 + w * 16 + j;
        if (bcnt == 2) {                      // overflow: rare wave-any
          if (b0d < tmax) INSERT(b0d, b0n);   // recheck: tmax may have tightened
          b0d = b1d; b0n = b1n;
          b1d = d;   b1n = n;
        } else if (bcnt == 1) {
          b1d = d; b1n = n; bcnt = 2;
        } else {
          b0d = d; b0n = n; bcnt = 1;
        }
      }
    }
    // end-of-tile drain (recheck each; order: b0 is older)
    if (bcnt >= 1 && b0d < tmax) INSERT(b0d, b0n);
    if (bcnt == 2 && b1d < tmax) INSERT(b1d, b1n);
  }

  // ---- merge 4 quarter-lists per row (stride 37 -> 2-way banking = free) ----
  __syncthreads();
  float* mv = (float*)&S[0];                    // reuse dead staging LDS
  int*   mi = (int*)((char*)&S[0] + 64 * 37 * 4);
#pragma unroll
  for (int k = 0; k < K_; ++k) {
    mv[lane * 37 + w * K_ + k] = tv[k];
    mi[lane * 37 + w * K_ + k] = ti[k];
  }
  __syncthreads();
  if (tid < 64) {
    float fv[K_]; int fi[K_];
    float mx = 3.4e38f; int mp = 0;
#pragma unroll
    for (int k = 0; k < K_; ++k) { fv[k] = 3.4e38f; fi[k] = 0; }
    for (int s = 0; s < 36; ++s) {
      float v = mv[tid * 37 + s]; int id = mi[tid * 37 + s];
      if (v < mx) {
#pragma unroll
        for (int k = 0; k < K_; ++k) if (k == mp) { fv[k] = v; fi[k] = id; }
        float m2 = fv[0]; int p2 = 0;
#pragma unroll
        for (int k = 1; k < K_; ++k) if (fv[k] > m2) { m2 = fv[k]; p2 = k; }
        mx = m2; mp = p2;
      }
    }
#pragma unroll
    for (int k = 0; k < K_; ++k)
      idxw[((size_t)b * M_ + r0 + tid) * K_ + k] = fi[k];
  }
}

// ---------------------------------------------------------------------------
// prep2: P/Q projection GEMM (runs AFTER knn; reuses the dead xhi/xlo region).
//   P[m] = x_m @ (W1[0:C] - W1[C:2C]) + b1,  Q[m] = x_m @ W1[C:2C]
// ---------------------------------------------------------------------------
__global__ __launch_bounds__(256) void prep2_kernel(
    const float* __restrict__ x, const float* __restrict__ W1,
    const float* __restrict__ b1, float* __restrict__ P, float* __restrict__ Q) {
  __shared__ float Xt[C_][64];
  __shared__ float Wt[C_][64];
  const int b = blockIdx.y, m0 = blockIdx.x * 64;
  const int tid = threadIdx.x;
  const float* xb = x + (size_t)b * C_ * M_;

  for (int i = tid; i < C_ * 16; i += 256) {
    int c = i >> 4, j4 = (i & 15) << 2;
    *(float4*)&Xt[c][j4] = *(const float4*)&xb[(size_t)c * M_ + m0 + j4];
  }

  const int ty = tid >> 4, tx = tid & 15;
  for (int t = 0; t < 3; ++t) {
    const int u0 = t * 64;
    __syncthreads();
    for (int i = tid; i < C_ * 64; i += 256) {
      int cin = i >> 6, j = i & 63;
      int u = u0 + j;
      float wv;
      if (u < C_) wv = W1[cin * C_ + u] - W1[(C_ + cin) * C_ + u];
      else        wv = W1[(C_ + cin) * C_ + (u - C_)];
      Wt[cin][j] = wv;
    }
    __syncthreads();
    float acc[4][4] = {};
#pragma unroll 8
    for (int c = 0; c < C_; ++c) {
      float4 rr = *(const float4*)&Xt[c][ty << 2];
      float4 ww = *(const float4*)&Wt[c][tx << 2];
      acc[0][0] += rr.x * ww.x; acc[0][1] += rr.x * ww.y; acc[0][2] += rr.x * ww.z; acc[0][3] += rr.x * ww.w;
      acc[1][0] += rr.y * ww.x; acc[1][1] += rr.y * ww.y; acc[1][2] += rr.y * ww.z; acc[1][3] += rr.y * ww.w;
      acc[2][0] += rr.z * ww.x; acc[2][1] += rr.z * ww.y; acc[2][2] += rr.z * ww.z; acc[2][3] += rr.z * ww.w;
      acc[3][0] += rr.w * ww.x; acc[3][1] += rr.w * ww.y; acc[3][2] += rr.w * ww.z; acc[3][3] += rr.w * ww.w;
    }
#pragma unroll
    for (int i = 0; i < 4; ++i) {
      int m = m0 + (ty << 2) + i;
      size_t base = ((size_t)b * M_ + m) * C_;
#pragma unroll
      for (int j = 0; j < 4; ++j) {
        int u = u0 + (tx << 2) + j;
        float v = acc[i][j];
        if (u < C_) P[base + u] = v + b1[u];
        else        Q[base + (u - C_)] = v;
      }
    }
  }
}

// ---------------------------------------------------------------------------
// edge_mlp: g[m] = mean_k LReLU(P[m] + Q[idx[m,k]]); out = relu(g @ W2 + b2).
// ---------------------------------------------------------------------------
__global__ __launch_bounds__(256) void edge_mlp_kernel(
    const float* __restrict__ P, const float* __restrict__ Q,
    const int* __restrict__ idxw, const float* __restrict__ W2,
    const float* __restrict__ b2, float* __restrict__ out) {
  __shared__ float g_l[C_][64];
  __shared__ float W2t[C_ * C_];
  const int b = blockIdx.y, m0 = blockIdx.x * 64;
  const int tid = threadIdx.x;

  for (int i = tid; i < (C_ * C_) / 4; i += 256)
    *(float4*)&W2t[i * 4] = *(const float4*)&W2[i * 4];

  const int ml = tid & 63, cg = tid >> 6;
  const int m = m0 + ml;
  const float* prow = P + ((size_t)b * M_ + m) * C_ + cg * 24;
  float pr[24];
#pragma unroll
  for (int t = 0; t < 24; t += 4) {
    float4 v = *(const float4*)(prow + t);
    pr[t] = v.x; pr[t + 1] = v.y; pr[t + 2] = v.z; pr[t + 3] = v.w;
  }
  float gacc[24] = {};
  const int* irow = idxw + ((size_t)b * M_ + m) * K_;
#pragma unroll
  for (int k = 0; k < K_; ++k) {
    int j = irow[k];
    const float* qrow = Q + ((size_t)b * M_ + j) * C_ + cg * 24;
#pragma unroll
    for (int t = 0; t < 24; t += 4) {
      float4 qv = *(const float4*)(qrow + t);
      float h;
      h = pr[t + 0] + qv.x; gacc[t + 0] += (h >= 0.f) ? h : 0.01f * h;
      h = pr[t + 1] + qv.y; gacc[t + 1] += (h >= 0.f) ? h : 0.01f * h;
      h = pr[t + 2] + qv.z; gacc[t + 2] += (h >= 0.f) ? h : 0.01f * h;
      h = pr[t + 3] + qv.w; gacc[t + 3] += (h >= 0.f) ? h : 0.01f * h;
    }
  }
#pragma unroll
  for (int t = 0; t < 24; ++t) g_l[cg * 24 + t][ml] = gacc[t] * (1.f / 9.f);
  __syncthreads();

  const int ty = tid >> 4, tx = tid & 15;
  float acc2[4][6] = {};
#pragma unroll 4
  for (int c = 0; c < C_; ++c) {
    float4 rr = *(const float4*)&g_l[c][ty << 2];
    float2 wa = *(const float2*)&W2t[c * C_ + tx * 6];
    float2 wb = *(const float2*)&W2t[c * C_ + tx * 6 + 2];
    float2 wc = *(const float2*)&W2t[c * C_ + tx * 6 + 4];
    float rv[4] = {rr.x, rr.y, rr.z, rr.w};
    float wv[6] = {wa.x, wa.y, wb.x, wb.y, wc.x, wc.y};
#pragma unroll
    for (int i = 0; i < 4; ++i)
#pragma unroll
      for (int j = 0; j < 6; ++j) acc2[i][j] += rv[i] * wv[j];
  }
#pragma unroll
  for (int i = 0; i < 4; ++i) {
    int mm = m0 + (ty << 2) + i;
#pragma unroll
    for (int j = 0; j < 6; ++j) {
      int u = tx * 6 + j;
      float v = acc2[i][j] + b2[u];
      v = fmaxf(v, 0.f);
      out[((size_t)b * C_ + u) * M_ + mm] = v;
    }
  }
}

extern "C" void kernel_launch(void* const* d_in, const int* in_sizes, int n_in,
                              void* d_out, int out_size, void* d_ws, size_t ws_size,
                              hipStream_t stream) {
  const float* x  = (const float*)d_in[0];
  const float* W1 = (const float*)d_in[1];
  const float* b1 = (const float*)d_in[2];
  const float* W2 = (const float*)d_in[3];
  const float* b2 = (const float*)d_in[4];
  float* out = (float*)d_out;

  // ws layout — peak 26,476,544 B (== round-1/2 proven footprint; do NOT grow):
  //   [0,        131072)    sq
  //   [131072,   1310720)   idxw
  //   phase 1 (prep1+knn):  xhi [1310720, 8126464), xlo [8126464, 14942208)
  //   phase 2 (prep2+mlp):  P   [1310720, 13893632), Q  [13893632, 26476544)
  //   (P/Q alias the dead xhi/xlo region; kernels are stream-ordered)
  char* ws = (char*)d_ws;
  float* sq  = (float*)ws;
  int* idxw  = (int*)(ws + 131072);
  unsigned short* xhi = (unsigned short*)(ws + 1310720);
  unsigned short* xlo = (unsigned short*)(ws + 8126464);
  float* P = (float*)(ws + 1310720);
  float* Q = (float*)(ws + 13893632);

  dim3 grid(M_ / 64, B_), blk(256);
  prep1_kernel<<<grid, blk, 0, stream>>>(x, sq, xhi, xlo);
  knn_kernel<<<grid, blk, 0, stream>>>(xhi, xlo, sq, idxw);
  prep2_kernel<<<grid, blk, 0, stream>>>(x, W1, b1, P, Q);
  edge_mlp_kernel<<<grid, blk, 0, stream>>>(P, Q, idxw, W2, b2, out);
}